// Round 8
// baseline (262.799 us; speedup 1.0000x reference)
//
#include <hip/hip_runtime.h>
#include <math.h>

#define NT     512
#define NWAVES 8
#define GB     2
#define NTOK   20
#define MROWS  (GB * NTOK)   // 40 real rows; M-tiles = 3 (rows 40-47 = ghost)

typedef _Float16 f16x8 __attribute__((ext_vector_type(8)));
typedef float    f32x4 __attribute__((ext_vector_type(4)));

// ---- ws layout (halves): transposed, zero-padded fp16 weights W_T[n][kpad]
#define WS_W1A  0        // [160][32]   (N=150,K=13)
#define WS_W1B  5120     // [112][160]  (N=100,K=150)
#define WS_WA0  23040    // [112][128]  (N=100,K=100)  wa0 rows 0..99 (h1 part)
#define WS_WA1  37376    // [112][128]
#define WS_W2A  51712    // [112][128]
#define WS_W2B  66048    // [64][128]   (N=50,K=100)
#define WS_W3A  74240    // [160][64]   (N=150,K=56)
#define WS_W3B  84480    // [112][160]  (N=100,K=150)
#define WS_W3C  102400   // [112][128]  (N=100,K=100)
#define WS_WA0H 116736   // [112][128]  (N=100,K=100)  wa0 rows 100..199 (g part)
#define WS_WA2  131072   // [16][128]   (N=1,  K=100)
#define WS_TOTAL 133120

// ---- LDS arena (halves), 40-row regions; ghost rows 40-47 alias forward.
// Ghost-write audit: t1->R1 head (pre-h1, overwritten); h1->R3 head (gq zone,
// rewritten P4); s1/f1 -> inside R2 (dead t1 zone); s2 -> dead PAD; f -> dead
// s2 rows. Scalars live AFTER the pad so no ghost clobbers them.
#define LH_R2   0        // [40][168] : t1 -> s1 -> f1 ; head: hc [16][136]
#define LH_R1   6720     // [40][136] : h1 ; tail: mv[16][72]@+0, ha[16][168]@+1152
#define LH_R3   12160    // [40][136] : A0[40][40] -> gq[16][136] -> s2 -> f[40][72], hb[16][136]
#define LH_PAD  17600    // 1088 halves: s2 ghost-row landing zone
#define LH_MV   (LH_R1 + 0)
#define LH_HA   (LH_R1 + 1152)
#define LH_HB   (LH_R3 + 0)
#define LH_HC   (LH_R2 + 0)
#define LH_GQ   (LH_R3 + 0)
#define LF_GB   9344     // f32 idx: gbias 200
#define LF_ATT  9544     // f32: att 48 (rows 40-47 ghost scores land in 40..47)
#define LF_SS   9592     // f32: 12
#define LDS_DW  9604
#define LDS_BYTES (LDS_DW * 4)   // 38416 B -> 4 blocks/CU

// ---------------------------------------------------------------------------
// prep: W_T[n][k] = (fp16) W[k][N..], zero-padded in both n and k
// ---------------------------------------------------------------------------
__device__ __forceinline__ void prep_one(const float* __restrict__ src, _Float16* dst,
                                         int local, int N, int K, int Ks)
{
    int n = local / Ks, k = local - n * Ks;
    dst[local] = (_Float16)((n < N && k < K) ? src[k * N + n] : 0.f);
}

__global__ __launch_bounds__(256)
void prep_kernel(const float* __restrict__ w1a, const float* __restrict__ w1b,
                 const float* __restrict__ wa0, const float* __restrict__ wa1,
                 const float* __restrict__ w2a, const float* __restrict__ w2b,
                 const float* __restrict__ w3a, const float* __restrict__ w3b,
                 const float* __restrict__ w3c, const float* __restrict__ wa2,
                 _Float16* __restrict__ ws)
{
    int g = blockIdx.x * 256 + threadIdx.x;
    if (g >= WS_TOTAL) return;
    if (g < WS_W1B)       prep_one(w1a, ws + WS_W1A, g - WS_W1A, 150, 13, 32);
    else if (g < WS_WA0)  prep_one(w1b, ws + WS_W1B, g - WS_W1B, 100, 150, 160);
    else if (g < WS_WA1)  prep_one(wa0, ws + WS_WA0, g - WS_WA0, 100, 100, 128);
    else if (g < WS_W2A)  prep_one(wa1, ws + WS_WA1, g - WS_WA1, 100, 100, 128);
    else if (g < WS_W2B)  prep_one(w2a, ws + WS_W2A, g - WS_W2A, 100, 100, 128);
    else if (g < WS_W3A)  prep_one(w2b, ws + WS_W2B, g - WS_W2B,  50, 100, 128);
    else if (g < WS_W3B)  prep_one(w3a, ws + WS_W3A, g - WS_W3A, 150,  56, 64);
    else if (g < WS_W3C)  prep_one(w3b, ws + WS_W3B, g - WS_W3B, 100, 150, 160);
    else if (g < WS_WA0H) prep_one(w3c, ws + WS_W3C, g - WS_W3C, 100, 100, 128);
    else if (g < WS_WA2)  prep_one(wa0 + 100 * 100, ws + WS_WA0H, g - WS_WA0H, 100, 100, 128);
    else                  prep_one(wa2, ws + WS_WA2, g - WS_WA2, 1, 100, 128);
}

// ---------------------------------------------------------------------------
// MFMA epilogue. C/D mapping (m89-verified): col = lane&15, row = (lane>>4)*4+r
// OMODE 0: fp16 strided LDS store. 1: f32 gbias[row*100+col] (rows<GB).
// 2: f32 att[row] (col 0 only; ghost rows 40-47 land in att[40..47] pad).
// ---------------------------------------------------------------------------
template<bool RELU, int BMODE, int OMODE>
__device__ __forceinline__ void epi_store(f32x4 acc, int mt, int nt, int cl, int kq,
                                          const float* __restrict__ biasg,
                                          const float* gbias, int Ncols,
                                          _Float16* C, int Cs)
{
    const int col = nt * 16 + cl;
    float bv = 0.f;
    if (BMODE == 0) bv = (col < Ncols) ? biasg[col] : 0.f;
#pragma unroll
    for (int r = 0; r < 4; ++r) {
        const int row = mt * 16 + kq * 4 + r;
        float y = acc[r];
        if (BMODE == 1) {
            int b = row / NTOK; if (b >= GB) b = 0;   // ghost rows: safe index
            y += (col < Ncols) ? gbias[b * 100 + col] : 0.f;
        } else {
            y += bv;
        }
        if (RELU) y = fmaxf(y, 0.f);
        if (OMODE == 0) {
            C[row * Cs + col] = (_Float16)y;
        } else if (OMODE == 1) {
            if (row < GB && col < Ncols) ((float*)C)[row * 100 + col] = y;
        } else {
            if (cl == 0 && nt == 0) ((float*)C)[row] = y;
        }
    }
}

// ---------------------------------------------------------------------------
// Tiled GEMM: item = N-tile; wave prefetches its B-frags, then M-sweep.
// Ghost M-rows (40-47) read aliased-finite LDS and write to dead zones.
// ---------------------------------------------------------------------------
template<int KT, int NTL, int MTN, bool RELU, int BMODE, int OMODE>
__device__ __forceinline__ void gemm_tok(const _Float16* A, const int As,
                                         const _Float16* __restrict__ BT, const int Bs,
                                         const float* __restrict__ biasg,
                                         const float* gbias, const int Ncols,
                                         _Float16* C, const int Cs,
                                         const int wv, const int lane)
{
    const int cl = lane & 15, kq = lane >> 4;
    constexpr int IPW = (NTL + NWAVES - 1) / NWAVES;
    f16x8 bf[IPW][KT];
#pragma unroll
    for (int ii = 0; ii < IPW; ++ii) {
        const int nt = wv + ii * NWAVES;
        if (nt < NTL) {
            const _Float16* Bp = BT + (nt * 16 + cl) * Bs + kq * 8;
#pragma unroll
            for (int kt = 0; kt < KT; ++kt) bf[ii][kt] = *(const f16x8*)(Bp + kt * 32);
        }
    }
#pragma unroll
    for (int ii = 0; ii < IPW; ++ii) {
        const int nt = wv + ii * NWAVES;
        if (nt >= NTL) break;
#pragma unroll
        for (int mt = 0; mt < MTN; ++mt) {
            const _Float16* Ap = A + (mt * 16 + cl) * As + kq * 8;
            f16x8 af[KT];
#pragma unroll
            for (int kt = 0; kt < KT; ++kt) af[kt] = *(const f16x8*)(Ap + kt * 32);
            f32x4 acc = {0.f, 0.f, 0.f, 0.f};
#pragma unroll
            for (int kt = 0; kt < KT; ++kt)
                acc = __builtin_amdgcn_mfma_f32_16x16x32_f16(af[kt], bf[ii][kt], acc, 0, 0, 0);
            epi_store<RELU, BMODE, OMODE>(acc, mt, nt, cl, kq, biasg, gbias, Ncols, C, Cs);
        }
    }
}

__global__ __launch_bounds__(NT, 8)
void vnet_kernel(const float* __restrict__ x,
                 const float* __restrict__ b1a, const float* __restrict__ b1b,
                 const float* __restrict__ ba0, const float* __restrict__ ba1,
                 const float* __restrict__ ba2,
                 const float* __restrict__ b2a, const float* __restrict__ b2b,
                 const float* __restrict__ b3a, const float* __restrict__ b3b,
                 const float* __restrict__ b3c,
                 const float* __restrict__ w3d, const float* __restrict__ b3d,
                 const _Float16* __restrict__ wsh,
                 float* __restrict__ outp)
{
    extern __shared__ float lds_f[];
    _Float16* lds_h = (_Float16*)lds_f;

    const int tid  = threadIdx.x;
    const int lane = tid & 63, wv = tid >> 6;
    const int b0   = blockIdx.x * GB;

    _Float16* A0  = lds_h + LH_R3;     // [40][40] in R3 head (dead until gq)
    _Float16* gqh = lds_h + LH_GQ;     // [16][136] over A0 (after A0 dies)
    float* ss    = lds_f + LF_SS;
    float* gbias = lds_f + LF_GB;
    float* att   = lds_f + LF_ATT;

    // ---- P0: zero arena (finite/zero base state for all pad reads) -------
    for (int i = tid; i < LDS_DW; i += NT) lds_f[i] = 0.f;
    __syncthreads();

    // ---- P1: x -> A0 fp16 [40][40]; stash self_state ---------------------
    const float* xg = x + (size_t)b0 * (NTOK * 13);
    for (int t = tid; t < GB * NTOK * 13; t += NT) {
        int row = t / 13, d = t - row * 13;
        A0[row * 40 + d] = (_Float16)xg[t];
    }
    if (tid < GB * 6) {
        int b = tid / 6, d = tid - b * 6;
        ss[tid] = xg[b * (NTOK * 13) + d];   // x[b,0,d]
    }
    __syncthreads();

    // ---- P2: t1 = relu(x @ w1a + b1a) -> R2 [40][168] --------------------
    gemm_tok<1, 10, 3, true, 0, 0>(A0, 40, wsh + WS_W1A, 32, b1a, nullptr, 150,
                                   lds_h + LH_R2, 168, wv, lane);
    __syncthreads();

    // ---- P3: h1 = relu(t1 @ w1b + b1b) -> R1 [40][136] -------------------
    gemm_tok<5, 7, 3, true, 0, 0>(lds_h + LH_R2, 168, wsh + WS_W1B, 160, b1b,
                                  nullptr, 100, lds_h + LH_R1, 136, wv, lane);
    __syncthreads();

    // ---- P4: gq fp16 strip [16][136] in R3 head (A0 dead) ----------------
    const _Float16* h1 = lds_h + LH_R1;
    for (int t = tid; t < GB * 100; t += NT) {
        int b = t / 100, c = t - b * 100;
        float s = 0.f;
#pragma unroll
        for (int n = 0; n < NTOK; ++n) s += (float)h1[(b * NTOK + n) * 136 + c];
        gqh[b * 136 + c] = (_Float16)(s * (1.f / NTOK));
    }
    __syncthreads();

    // ---- P5: gbias[b][c] = ba0[c] + gq[b] @ wa0_hi  (MFMA, f32 out) ------
    gemm_tok<4, 7, 1, false, 0, 1>(gqh, 136, wsh + WS_WA0H, 128, ba0, nullptr, 100,
                                   (_Float16*)gbias, 0, wv, lane);
    __syncthreads();

    // ---- P6: s1 = relu(h1 @ wa0_lo + gbias) -> R2 (t1 dead) --------------
    gemm_tok<4, 7, 3, true, 1, 0>(h1, 136, wsh + WS_WA0, 128, nullptr, gbias, 100,
                                  lds_h + LH_R2, 136, wv, lane);
    __syncthreads();

    // ---- P7: s2 = relu(s1 @ wa1 + ba1) -> R3 (gq dead) -------------------
    gemm_tok<4, 7, 3, true, 0, 0>(lds_h + LH_R2, 136, wsh + WS_WA1, 128, ba1,
                                  nullptr, 100, lds_h + LH_R3, 136, wv, lane);
    __syncthreads();

    // ---- P8: scores = s2 @ wa2 (MFMA, wave 7); f1 -> R2 (waves 0-6) ------
    gemm_tok<4, 1, 3, false, 0, 2>(lds_h + LH_R3, 136, wsh + WS_WA2, 128, ba2,
                                   nullptr, 1, (_Float16*)att, 0,
                                   (NWAVES - 1) - wv, lane);
    gemm_tok<4, 7, 3, true, 0, 0>(h1, 136, wsh + WS_W2A, 128, b2a, nullptr, 100,
                                  lds_h + LH_R2, 136, wv, lane);
    __syncthreads();

    // ---- P9: f = f1 @ w2b -> R3 [40][72] (waves 0-3); softmax (waves 4-5)
    gemm_tok<4, 4, 3, false, 0, 0>(lds_h + LH_R2, 136, wsh + WS_W2B, 128, b2b,
                                   nullptr, 50, lds_h + LH_R3, 72, wv, lane);
    if (wv >= 4 && lane == 0) {
        int b = wv - 4;
        if (b < GB) {
            float* a = att + b * NTOK;
            float mx = a[0];
#pragma unroll
            for (int n = 1; n < NTOK; ++n) mx = fmaxf(mx, a[n]);
            float s = 0.f;
#pragma unroll
            for (int n = 0; n < NTOK; ++n) { float e = expf(a[n] - mx); a[n] = e; s += e; }
            float inv = 1.f / s;
#pragma unroll
            for (int n = 0; n < NTOK; ++n) a[n] *= inv;
        }
    }
    __syncthreads();

    // ---- P10: mv = [ss | wf] fp16 [16][72] -> R1 head (h1 dead) ----------
    _Float16* mv = lds_h + LH_MV;
    const _Float16* fh = lds_h + LH_R3;
    for (int t = tid; t < GB * 56; t += NT) {
        int b = t / 56, c = t - b * 56;
        float v;
        if (c < 6) {
            v = ss[b * 6 + c];
        } else {
            int cc = c - 6;
            float acc = 0.f;
            const float* ab = att + b * NTOK;
#pragma unroll
            for (int n = 0; n < NTOK; ++n)
                acc = fmaf((float)fh[(b * NTOK + n) * 72 + cc], ab[n], acc);
            v = acc;
        }
        mv[b * 72 + c] = (_Float16)v;
    }
    __syncthreads();

    // ---- T1: ha = relu(mv @ w3a + b3a)  [16][168] @ R1+1152 --------------
    gemm_tok<2, 10, 1, true, 0, 0>(mv, 72, wsh + WS_W3A, 64, b3a, nullptr, 150,
                                   lds_h + LH_HA, 168, wv, lane);
    __syncthreads();

    // ---- T2: hb = relu(ha @ w3b + b3b)  [16][136] @ R3 head (f dead after P10)
    gemm_tok<5, 7, 1, true, 0, 0>(lds_h + LH_HA, 168, wsh + WS_W3B, 160, b3b,
                                  nullptr, 100, lds_h + LH_HB, 136, wv, lane);
    __syncthreads();

    // ---- T3: hc = relu(hb @ w3c + b3c)  [16][136] @ R2 head --------------
    gemm_tok<4, 7, 1, true, 0, 0>(lds_h + LH_HB, 136, wsh + WS_W3C, 128, b3c,
                                  nullptr, 100, lds_h + LH_HC, 136, wv, lane);
    __syncthreads();

    // ---- T4: out = hc @ w3d + b3d ----------------------------------------
    if (tid < GB) {
        const _Float16* ib = lds_h + LH_HC + tid * 136;
        float acc = b3d[0];
#pragma unroll 4
        for (int k = 0; k < 100; ++k) acc = fmaf((float)ib[k], w3d[k], acc);
        outp[b0 + tid] = acc;
    }
}

extern "C" void kernel_launch(void* const* d_in, const int* in_sizes, int n_in,
                              void* d_out, int out_size, void* d_ws, size_t ws_size,
                              hipStream_t stream)
{
    const float* x   = (const float*)d_in[0];
    const float* w1a = (const float*)d_in[1];
    const float* b1a = (const float*)d_in[2];
    const float* w1b = (const float*)d_in[3];
    const float* b1b = (const float*)d_in[4];
    const float* wa0 = (const float*)d_in[5];
    const float* ba0 = (const float*)d_in[6];
    const float* wa1 = (const float*)d_in[7];
    const float* ba1 = (const float*)d_in[8];
    const float* wa2 = (const float*)d_in[9];
    const float* ba2 = (const float*)d_in[10];
    const float* w2a = (const float*)d_in[11];
    const float* b2a = (const float*)d_in[12];
    const float* w2b = (const float*)d_in[13];
    const float* b2b = (const float*)d_in[14];
    const float* w3a = (const float*)d_in[15];
    const float* b3a = (const float*)d_in[16];
    const float* w3b = (const float*)d_in[17];
    const float* b3b = (const float*)d_in[18];
    const float* w3c = (const float*)d_in[19];
    const float* b3c = (const float*)d_in[20];
    const float* w3d = (const float*)d_in[21];
    const float* b3d = (const float*)d_in[22];
    float* outp = (float*)d_out;
    _Float16* wsh = (_Float16*)d_ws;

    hipFuncSetAttribute((const void*)vnet_kernel,
                        hipFuncAttributeMaxDynamicSharedMemorySize, LDS_BYTES);

    hipLaunchKernelGGL(prep_kernel, dim3((WS_TOTAL + 255) / 256), dim3(256), 0, stream,
                       w1a, w1b, wa0, wa1, w2a, w2b, w3a, w3b, w3c, wa2, wsh);

    const int B = 16384;
    hipLaunchKernelGGL(vnet_kernel, dim3(B / GB), dim3(NT), LDS_BYTES, stream,
                       x, b1a, b1b, ba0, ba1, ba2, b2a, b2b,
                       b3a, b3b, b3c, w3d, b3d, wsh, outp);
}

// Round 9
// 171.439 us; speedup vs baseline: 1.5329x; 1.5329x over previous
//
#include <hip/hip_runtime.h>
#include <math.h>

#define NT     512
#define NWAVES 8
#define GB     4
#define NTOK   20
#define NTT_P  5          // token tiles for 80-row phases

typedef _Float16 f16x8 __attribute__((ext_vector_type(8)));
typedef _Float16 f16x4 __attribute__((ext_vector_type(4)));
typedef float    f32x4 __attribute__((ext_vector_type(4)));

// ---- ws fp16 section: transposed, zero-padded weights W_T[n][kpad] --------
#define WS_W1A  0        // [160][32]   (N=150,K=13)
#define WS_W1B  5120     // [112][160]  (N=100,K=150)
#define WS_WA0  23040    // [112][128]  (N=100,K=100)  wa0 rows 0..99
#define WS_WA1  37376    // [112][128]
#define WS_W2A  51712    // [112][128]
#define WS_W2B  66048    // [64][128]   (N=50,K=100)
#define WS_W3A  74240    // [160][64]   (N=150,K=56)
#define WS_W3B  84480    // [112][160]  (N=100,K=150)
#define WS_W3C  102400   // [112][128]  (N=100,K=100)
#define WS_WA0H 116736   // [112][128]  wa0 rows 100..199 (g part)
#define WS_WA2  131072   // [16][128]   (N=1,K=100)
#define WS_TOTAL 133120
// ---- ws f32 bias section (zero-padded), float index from ws base ----------
#define WB_BASE 66560    // = WS_TOTAL/2 (f32 units)
#define WB_B1A  0        // 160 (150)
#define WB_B1B  160      // 112 (100)
#define WB_BA0  272      // 112 (100)
#define WB_BA1  384      // 112 (100)
#define WB_B2A  496      // 112 (100)
#define WB_B2B  608      // 64  (50)
#define WB_B3A  672      // 160 (150)
#define WB_B3B  832      // 112 (100)
#define WB_B3C  944      // 112 (100)
#define WB_N    1056
#define PREP_TOTAL (WS_TOTAL + WB_N)

// ---- LDS arena (halves). Activations row-major [token][feat], strides
// chosen 16B-aligned and !=0 mod 32dw (2-way max bank aliasing).
#define LH_R1   0        // 13440: t1[80][168] -> s1[80][136] -> f1[80][136];
                         //        tail: ha[16][168]@+0, hc[16][136]@+4096
#define LH_R2   13440    // 10880: h1[80][136] -> hb[16][136]
#define LH_R3   24320    // 10880: x[80][40] -> gq[16][136] -> s2[80][136]
                         //        -> f[80][72]@+0, mv[16][72]@+8000
#define LH_HA   (LH_R1 + 0)
#define LH_HC   (LH_R1 + 4096)
#define LH_HB   (LH_R2 + 0)
#define LH_GQ   (LH_R3 + 0)
#define LH_F    (LH_R3 + 0)
#define LH_MV   (LH_R3 + 8000)
#define LF_GB   17600    // f32: gbias [4][112]
#define LF_ATT  18048    // f32: att [80]
#define LF_SS   18128    // f32: ss [24]
#define LDS_DW  18152
#define LDS_BYTES (LDS_DW * 4)   // 72608 B -> 2 blocks/CU

// ---------------------------------------------------------------------------
// prep: W_T[n][k] = (fp16) W[k][N..] zero-padded; plus zero-padded f32 biases
// ---------------------------------------------------------------------------
__device__ __forceinline__ void prep_one(const float* __restrict__ src, _Float16* dst,
                                         int local, int N, int K, int Ks)
{
    int n = local / Ks, k = local - n * Ks;
    dst[local] = (_Float16)((n < N && k < K) ? src[k * N + n] : 0.f);
}
__device__ __forceinline__ void prep_b(const float* __restrict__ src, float* dst,
                                       int idx, int N)
{
    dst[idx] = (idx < N) ? src[idx] : 0.f;
}

__global__ __launch_bounds__(256)
void prep_kernel(const float* __restrict__ w1a, const float* __restrict__ w1b,
                 const float* __restrict__ wa0, const float* __restrict__ wa1,
                 const float* __restrict__ w2a, const float* __restrict__ w2b,
                 const float* __restrict__ w3a, const float* __restrict__ w3b,
                 const float* __restrict__ w3c, const float* __restrict__ wa2,
                 const float* __restrict__ b1a, const float* __restrict__ b1b,
                 const float* __restrict__ ba0, const float* __restrict__ ba1,
                 const float* __restrict__ b2a, const float* __restrict__ b2b,
                 const float* __restrict__ b3a, const float* __restrict__ b3b,
                 const float* __restrict__ b3c,
                 _Float16* __restrict__ ws)
{
    int g = blockIdx.x * 256 + threadIdx.x;
    if (g >= PREP_TOTAL) return;
    if (g >= WS_TOTAL) {
        float* wb = (float*)ws + WB_BASE;
        int l = g - WS_TOTAL;
        if (l < WB_B1B)      prep_b(b1a, wb + WB_B1A, l - WB_B1A, 150);
        else if (l < WB_BA0) prep_b(b1b, wb + WB_B1B, l - WB_B1B, 100);
        else if (l < WB_BA1) prep_b(ba0, wb + WB_BA0, l - WB_BA0, 100);
        else if (l < WB_B2A) prep_b(ba1, wb + WB_BA1, l - WB_BA1, 100);
        else if (l < WB_B2B) prep_b(b2a, wb + WB_B2A, l - WB_B2A, 100);
        else if (l < WB_B3A) prep_b(b2b, wb + WB_B2B, l - WB_B2B, 50);
        else if (l < WB_B3B) prep_b(b3a, wb + WB_B3A, l - WB_B3A, 150);
        else if (l < WB_B3C) prep_b(b3b, wb + WB_B3B, l - WB_B3B, 100);
        else                 prep_b(b3c, wb + WB_B3C, l - WB_B3C, 100);
        return;
    }
    if (g < WS_W1B)       prep_one(w1a, ws + WS_W1A, g - WS_W1A, 150, 13, 32);
    else if (g < WS_WA0)  prep_one(w1b, ws + WS_W1B, g - WS_W1B, 100, 150, 160);
    else if (g < WS_WA1)  prep_one(wa0, ws + WS_WA0, g - WS_WA0, 100, 100, 128);
    else if (g < WS_W2A)  prep_one(wa1, ws + WS_WA1, g - WS_WA1, 100, 100, 128);
    else if (g < WS_W2B)  prep_one(w2a, ws + WS_W2A, g - WS_W2A, 100, 100, 128);
    else if (g < WS_W3A)  prep_one(w2b, ws + WS_W2B, g - WS_W2B,  50, 100, 128);
    else if (g < WS_W3B)  prep_one(w3a, ws + WS_W3A, g - WS_W3A, 150,  56, 64);
    else if (g < WS_W3C)  prep_one(w3b, ws + WS_W3B, g - WS_W3B, 100, 150, 160);
    else if (g < WS_WA0H) prep_one(w3c, ws + WS_W3C, g - WS_W3C, 100, 100, 128);
    else if (g < WS_WA2)  prep_one(wa0 + 100 * 100, ws + WS_WA0H, g - WS_WA0H, 100, 100, 128);
    else                  prep_one(wa2, ws + WS_WA2, g - WS_WA2, 1, 100, 128);
}

// ---------------------------------------------------------------------------
// Swapped-operand GEMM: D = mfma(W_frag, X_frag) -> D[feature][token].
// a-frag = W_T row (global, prefetched per item); b-frag = activation row
// (LDS [token][Xs], ds_read_b128). Lane(cl,kq) of tile (mt,nt) holds 4
// consecutive features (mt*16+kq*4+r) for token (nt*16+cl) -> packed b64 store
// into row-major Y[token][feature].
// OMODE 0: fp16 Y store. 1: f32x4 -> gbias[token][feat] (token<GB).
// 2: f32 att[token] from (mt=0,kq=0,r=0).
// BMODE 0: bias = padded f32 biasp[feat..feat+3]. 1: gbias[token/20][feat..].
// ---------------------------------------------------------------------------
template<int KT, int MTL, int NTT, bool RELU, int BMODE, int OMODE>
__device__ __forceinline__ void gemm_sw(const _Float16* X, const int Xs,
                                        const _Float16* __restrict__ WT, const int Bs,
                                        const float* __restrict__ biasp,
                                        const float* gbias,
                                        _Float16* Y, const int Ys,
                                        const int wv, const int lane)
{
    const int cl = lane & 15, kq = lane >> 4;
    constexpr int IPW = (MTL + NWAVES - 1) / NWAVES;
    f16x8 wf[IPW][KT];
    f32x4 bv[IPW];
#pragma unroll
    for (int ii = 0; ii < IPW; ++ii) {
        const int mt = wv + ii * NWAVES;
        if (mt < MTL) {
            const _Float16* Wp = WT + (mt * 16 + cl) * Bs + kq * 8;
#pragma unroll
            for (int kt = 0; kt < KT; ++kt) wf[ii][kt] = *(const f16x8*)(Wp + kt * 32);
            if (OMODE != 2 && BMODE == 0)
                bv[ii] = *(const f32x4*)(biasp + mt * 16 + kq * 4);
        }
    }
#pragma unroll
    for (int ii = 0; ii < IPW; ++ii) {
        const int mt = wv + ii * NWAVES;
        if (mt >= MTL) break;
        const int fb = mt * 16 + kq * 4;
#pragma unroll
        for (int nt = 0; nt < NTT; ++nt) {
            const _Float16* Xp = X + (nt * 16 + cl) * Xs + kq * 8;
            f16x8 xf[KT];
#pragma unroll
            for (int kt = 0; kt < KT; ++kt) xf[kt] = *(const f16x8*)(Xp + kt * 32);
            f32x4 acc = {0.f, 0.f, 0.f, 0.f};
#pragma unroll
            for (int kt = 0; kt < KT; ++kt)
                acc = __builtin_amdgcn_mfma_f32_16x16x32_f16(wf[ii][kt], xf[kt], acc, 0, 0, 0);
            const int token = nt * 16 + cl;
            if (OMODE == 2) {
                if (kq == 0) ((float*)Y)[token] = acc[0] + biasp[0];
            } else if (OMODE == 1) {
                if (cl < GB) {
                    f32x4 o = acc + bv[ii];
                    *(f32x4*)((float*)Y + cl * 112 + fb) = o;
                }
            } else {
                f32x4 bb;
                if (BMODE == 1)
                    bb = *(const f32x4*)(gbias + (token / NTOK) * 112 + fb);
                else
                    bb = bv[ii];
                f32x4 y = acc + bb;
                if (RELU) {
                    y[0] = fmaxf(y[0], 0.f); y[1] = fmaxf(y[1], 0.f);
                    y[2] = fmaxf(y[2], 0.f); y[3] = fmaxf(y[3], 0.f);
                }
                f16x4 o = { (_Float16)y[0], (_Float16)y[1],
                            (_Float16)y[2], (_Float16)y[3] };
                *(f16x4*)(Y + token * Ys + fb) = o;
            }
        }
    }
}

__global__ __launch_bounds__(NT, 4)
void vnet_kernel(const float* __restrict__ x,
                 const float* __restrict__ ba2,
                 const float* __restrict__ w3d, const float* __restrict__ b3d,
                 const _Float16* __restrict__ wsh,
                 float* __restrict__ outp)
{
    extern __shared__ float lds_f[];
    _Float16* lds_h = (_Float16*)lds_f;

    const int tid  = threadIdx.x;
    const int lane = tid & 63, wv = tid >> 6;
    const int b0   = blockIdx.x * GB;
    const float* wb = (const float*)wsh + WB_BASE;

    _Float16* xa  = lds_h + LH_R3;   // x [80][40]
    _Float16* gqh = lds_h + LH_GQ;   // [16][136] over dead x
    float* gbias = lds_f + LF_GB;
    float* att   = lds_f + LF_ATT;
    float* ss    = lds_f + LF_SS;

    // ---- P0: zero arena (all later pad-reads must be finite) -------------
    for (int i = tid; i < LDS_DW; i += NT) lds_f[i] = 0.f;
    __syncthreads();

    // ---- P1: x -> LDS row-major [token][40] (no transpose); self_state ---
    const float* xg = x + (size_t)b0 * (NTOK * 13);
    for (int t = tid; t < GB * NTOK * 13; t += NT) {
        int row = t / 13, d = t - row * 13;
        xa[row * 40 + d] = (_Float16)xg[t];
    }
    if (tid < GB * 6) {
        int b = tid / 6, d = tid - b * 6;
        ss[tid] = xg[b * (NTOK * 13) + d];   // x[b,0,d]
    }
    __syncthreads();

    // ---- P2: t1 = relu(x @ w1a + b1a) -> R1 [80][168] --------------------
    gemm_sw<1, 10, NTT_P, true, 0, 0>(xa, 40, wsh + WS_W1A, 32, wb + WB_B1A,
                                      nullptr, lds_h + LH_R1, 168, wv, lane);
    __syncthreads();

    // ---- P3: h1 = relu(t1 @ w1b + b1b) -> R2 [80][136] -------------------
    gemm_sw<5, 7, NTT_P, true, 0, 0>(lds_h + LH_R1, 168, wsh + WS_W1B, 160,
                                     wb + WB_B1B, nullptr, lds_h + LH_R2, 136,
                                     wv, lane);
    __syncthreads();

    // ---- P4: gq[b][c] = mean_n h1[b*20+n][c] -> fp16 [16][136] (over x) --
    const _Float16* h1 = lds_h + LH_R2;
    for (int t = tid; t < GB * 100; t += NT) {
        int b = t / 100, c = t - b * 100;
        float s = 0.f;
#pragma unroll
        for (int n = 0; n < NTOK; ++n) s += (float)h1[(b * NTOK + n) * 136 + c];
        gqh[b * 136 + c] = (_Float16)(s * (1.f / NTOK));
    }
    __syncthreads();

    // ---- P5: gbias[b][feat] = ba0[feat] + gq[b] @ wa0_hi  (f32x4 out) ----
    gemm_sw<4, 7, 1, false, 0, 1>(gqh, 136, wsh + WS_WA0H, 128, wb + WB_BA0,
                                  nullptr, (_Float16*)gbias, 0, wv, lane);
    __syncthreads();

    // ---- P6: s1 = relu(h1 @ wa0_lo + gbias) -> R1 (t1 dead) --------------
    gemm_sw<4, 7, NTT_P, true, 1, 0>(h1, 136, wsh + WS_WA0, 128, nullptr,
                                     gbias, lds_h + LH_R1, 136, wv, lane);
    __syncthreads();

    // ---- P7: s2 = relu(s1 @ wa1 + ba1) -> R3 (x/gq dead) -----------------
    gemm_sw<4, 7, NTT_P, true, 0, 0>(lds_h + LH_R1, 136, wsh + WS_WA1, 128,
                                     wb + WB_BA1, nullptr, lds_h + LH_R3, 136,
                                     wv, lane);
    __syncthreads();

    // ---- P8: scores (wave 7, reads s2); f1 = relu(h1@w2a+b2a) -> R1 ------
    gemm_sw<4, 1, NTT_P, false, 0, 2>(lds_h + LH_R3, 136, wsh + WS_WA2, 128,
                                      ba2, nullptr, (_Float16*)att, 0,
                                      (NWAVES - 1) - wv, lane);
    gemm_sw<4, 7, NTT_P, true, 0, 0>(h1, 136, wsh + WS_W2A, 128, wb + WB_B2A,
                                     nullptr, lds_h + LH_R1, 136, wv, lane);
    __syncthreads();

    // ---- P9: f = f1 @ w2b + b2b -> R3 [80][72] (waves 0-3, s2 dead);
    //           softmax(att) per-b on waves 4-7 ----------------------------
    gemm_sw<4, 4, NTT_P, false, 0, 0>(lds_h + LH_R1, 136, wsh + WS_W2B, 128,
                                      wb + WB_B2B, nullptr, lds_h + LH_F, 72,
                                      wv, lane);
    if (wv >= 4 && lane == 0) {
        int b = wv - 4;
        if (b < GB) {
            float* a = att + b * NTOK;
            float mx = a[0];
#pragma unroll
            for (int n = 1; n < NTOK; ++n) mx = fmaxf(mx, a[n]);
            float s = 0.f;
#pragma unroll
            for (int n = 0; n < NTOK; ++n) { float e = expf(a[n] - mx); a[n] = e; s += e; }
            float inv = 1.f / s;
#pragma unroll
            for (int n = 0; n < NTOK; ++n) a[n] *= inv;
        }
    }
    __syncthreads();

    // ---- P10: mv[b][c] = [ss | wf] fp16 [16][72] @ R3+8000 ---------------
    _Float16* mv = lds_h + LH_MV;
    const _Float16* fh = lds_h + LH_F;
    for (int t = tid; t < GB * 56; t += NT) {
        int b = t / 56, c = t - b * 56;
        float v;
        if (c < 6) {
            v = ss[b * 6 + c];
        } else {
            int cc = c - 6;
            float acc = 0.f;
            const float* ab = att + b * NTOK;
#pragma unroll
            for (int n = 0; n < NTOK; ++n)
                acc = fmaf((float)fh[(b * NTOK + n) * 72 + cc], ab[n], acc);
            v = acc;
        }
        mv[b * 72 + c] = (_Float16)v;
    }
    __syncthreads();

    // ---- T1: ha = relu(mv @ w3a + b3a)  [16][168] @ R1 (f1 dead) ---------
    gemm_sw<2, 10, 1, true, 0, 0>(mv, 72, wsh + WS_W3A, 64, wb + WB_B3A,
                                  nullptr, lds_h + LH_HA, 168, wv, lane);
    __syncthreads();

    // ---- T2: hb = relu(ha @ w3b + b3b)  [16][136] @ R2 (h1 dead) ---------
    gemm_sw<5, 7, 1, true, 0, 0>(lds_h + LH_HA, 168, wsh + WS_W3B, 160,
                                 wb + WB_B3B, nullptr, lds_h + LH_HB, 136,
                                 wv, lane);
    __syncthreads();

    // ---- T3: hc = relu(hb @ w3c + b3c)  [16][136] @ R1+4096 --------------
    gemm_sw<4, 7, 1, true, 0, 0>(lds_h + LH_HB, 136, wsh + WS_W3C, 128,
                                 wb + WB_B3C, nullptr, lds_h + LH_HC, 136,
                                 wv, lane);
    __syncthreads();

    // ---- T4: out = hc @ w3d + b3d ----------------------------------------
    if (tid < GB) {
        const _Float16* ib = lds_h + LH_HC + tid * 136;
        float acc = b3d[0];
#pragma unroll 4
        for (int k = 0; k < 100; ++k) acc = fmaf((float)ib[k], w3d[k], acc);
        outp[b0 + tid] = acc;
    }
}

extern "C" void kernel_launch(void* const* d_in, const int* in_sizes, int n_in,
                              void* d_out, int out_size, void* d_ws, size_t ws_size,
                              hipStream_t stream)
{
    const float* x   = (const float*)d_in[0];
    const float* w1a = (const float*)d_in[1];
    const float* b1a = (const float*)d_in[2];
    const float* w1b = (const float*)d_in[3];
    const float* b1b = (const float*)d_in[4];
    const float* wa0 = (const float*)d_in[5];
    const float* ba0 = (const float*)d_in[6];
    const float* wa1 = (const float*)d_in[7];
    const float* ba1 = (const float*)d_in[8];
    const float* wa2 = (const float*)d_in[9];
    const float* ba2 = (const float*)d_in[10];
    const float* w2a = (const float*)d_in[11];
    const float* b2a = (const float*)d_in[12];
    const float* w2b = (const float*)d_in[13];
    const float* b2b = (const float*)d_in[14];
    const float* w3a = (const float*)d_in[15];
    const float* b3a = (const float*)d_in[16];
    const float* w3b = (const float*)d_in[17];
    const float* b3b = (const float*)d_in[18];
    const float* w3c = (const float*)d_in[19];
    const float* b3c = (const float*)d_in[20];
    const float* w3d = (const float*)d_in[21];
    const float* b3d = (const float*)d_in[22];
    float* outp = (float*)d_out;
    _Float16* wsh = (_Float16*)d_ws;

    hipFuncSetAttribute((const void*)vnet_kernel,
                        hipFuncAttributeMaxDynamicSharedMemorySize, LDS_BYTES);

    hipLaunchKernelGGL(prep_kernel, dim3((PREP_TOTAL + 255) / 256), dim3(256),
                       0, stream,
                       w1a, w1b, wa0, wa1, w2a, w2b, w3a, w3b, w3c, wa2,
                       b1a, b1b, ba0, ba1, b2a, b2b, b3a, b3b, b3c, wsh);

    const int B = 16384;
    hipLaunchKernelGGL(vnet_kernel, dim3(B / GB), dim3(NT), LDS_BYTES, stream,
                       x, ba2, w3d, b3d, wsh, outp);
}